// Round 9
// baseline (346.326 us; speedup 1.0000x reference)
//
#include <hip/hip_runtime.h>
#include <hip/hip_bf16.h>
#include <stdint.h>

#define MDIM 16384   // B*S = 4*4096
#define NDIM 2048    // MAX_OUT
#define KDIM 2048    // MAX_IN

typedef __attribute__((ext_vector_type(4))) float f32x4;
typedef __attribute__((ext_vector_type(8))) short s16x8;

__device__ __forceinline__ void gload_lds16(const __hip_bfloat16* g, void* l) {
    __builtin_amdgcn_global_load_lds(
        (const __attribute__((address_space(1))) void*)g,
        (__attribute__((address_space(3))) void*)l,
        16, 0, 0);
}

// ---------------- prep kernels (at HBM BW floor) ----------------

__global__ __launch_bounds__(256) void prep_x(
    const float* __restrict__ x, const float* __restrict__ weights,
    const float* __restrict__ a_scales, __hip_bfloat16* __restrict__ xq)
{
    float A0 = 0.f, A1 = 0.f;
    #pragma unroll
    for (int k = 0; k < 16; ++k) {
        float w = weights[k];
        if (((k >> 1) & 1) == 0) A0 += w; else A1 += w;
    }
    const float s0 = a_scales[0], s1 = a_scales[1];
    const float r0 = 1.f / s0, r1 = 1.f / s1;

    size_t idx = ((size_t)blockIdx.x * 256 + threadIdx.x) * 8;
    const f32x4* xv = (const f32x4*)(x + idx);
    f32x4 v0 = xv[0], v1 = xv[1];
    float vals[8] = {v0.x, v0.y, v0.z, v0.w, v1.x, v1.y, v1.z, v1.w};

    union { s16x8 v; __hip_bfloat16 h[8]; } u;
    #pragma unroll
    for (int j = 0; j < 8; ++j) {
        float q0 = rintf(fminf(fmaxf(vals[j] * r0, -8.f),   7.f)) * s0;
        float q1 = rintf(fminf(fmaxf(vals[j] * r1, -128.f), 127.f)) * s1;
        u.h[j] = __float2bfloat16(A0 * q0 + A1 * q1);
    }
    *(s16x8*)(xq + idx) = u.v;
}

__global__ __launch_bounds__(256) void prep_w(
    const float* __restrict__ W, const float* __restrict__ weights,
    const float* __restrict__ w_scales, __hip_bfloat16* __restrict__ wq)
{
    float c00 = weights[0] + weights[2]  + weights[4]  + weights[6];
    float c01 = weights[1] + weights[3]  + weights[5]  + weights[7];
    float c10 = weights[8] + weights[10] + weights[12] + weights[14];
    float c11 = weights[9] + weights[11] + weights[13] + weights[15];

    const float s0 = w_scales[0], s1 = w_scales[1];
    const float r0 = 1.f / s0, r1 = 1.f / s1;

    size_t idx = ((size_t)blockIdx.x * 256 + threadIdx.x) * 8;
    const int o = (int)(idx >> 11);
    const int c = (int)(idx & 2047);
    const bool inner = (o < 1024) && (c < 1024);
    const float k0 = inner ? (c00 + c10) : c10;
    const float k1 = inner ? (c01 + c11) : c11;

    const f32x4* wv = (const f32x4*)(W + idx);
    f32x4 v0 = wv[0], v1 = wv[1];
    float vals[8] = {v0.x, v0.y, v0.z, v0.w, v1.x, v1.y, v1.z, v1.w};

    union { s16x8 v; __hip_bfloat16 h[8]; } u;
    #pragma unroll
    for (int j = 0; j < 8; ++j) {
        float q0 = rintf(fminf(fmaxf(vals[j] * r0, -8.f),   7.f)) * s0;
        float q1 = rintf(fminf(fmaxf(vals[j] * r1, -128.f), 127.f)) * s1;
        u.h[j] = __float2bfloat16(k0 * q0 + k1 * q1);
    }
    *(s16x8*)(wq + idx) = u.v;
}

__global__ __launch_bounds__(256) void prep_b(
    const float* __restrict__ b, const float* __restrict__ weights,
    float* __restrict__ bm)
{
    int o = blockIdx.x * 256 + threadIdx.x;
    if (o >= NDIM) return;
    float S1 = 0.f, S0 = 0.f;
    #pragma unroll
    for (int k = 0; k < 8; ++k)  S0 += weights[k];
    #pragma unroll
    for (int k = 8; k < 16; ++k) S1 += weights[k];
    bm[o] = b[o] * ((o < 1024) ? (S0 + S1) : S1);
}

// ---------------- GEMM: 256x256 tile, 8 waves.
// A: global->VGPR direct (L2-resident panel, frag layout == row-major rows;
//    reg double-buffered one chunk ahead) — NO LDS traffic for A.
// B: LDS ring-4 of 16 KB slots (T2-swizzled, gload_lds staged 3 ahead),
//    bf frags ds_read one chunk ahead.
// Per chunk: [8 A-loads(c+1)] [2 B-gloads(c+3)] [4 bf ds_reads(c+1)]
//            [32 MFMA on A(c),bf(c)] [vmcnt(10)] [barrier].
// vmcnt(10) = |A(c+1)|+|B(c+3)| issued this chunk -> everything older
// (incl. B(c+2) staging) drained chip-wide before the barrier exits. ----

#define BM 256
#define BN 256
#define NCH 64           // K chunks of 32
#define BSLOT 16384      // bytes per B ring slot (256 rows x 64 B)

#define MFMA(a, b, c) __builtin_amdgcn_mfma_f32_16x16x32_bf16((a), (b), (c), 0, 0, 0)

// AFU/BFU: fragments of chunk c (ready). AFL/BFL: filled with chunk c+1.
// SB1 = (c+1)&3 (bf read slot), SB3 = (c+3)&3 (stage slot).
#define CHUNK(AFU, AFL, BFU, BFL, SB1, SB3)                                  \
  {                                                                          \
    const size_t au_ = (size_t)kgA * 64;                                     \
    _Pragma("unroll")                                                        \
    for (int m_ = 0; m_ < 8; ++m_)                                           \
      AFL[m_] = *(const s16x8*)(Abase + au_ + (size_t)m_ * 65536);           \
    gload_lds16(Bs0 + kgB * 32, lds + (SB3) * BSLOT + ldoff);                \
    gload_lds16(Bs1 + kgB * 32, lds + (SB3) * BSLOT + 8192 + ldoff);         \
    _Pragma("unroll")                                                        \
    for (int n_ = 0; n_ < 4; ++n_)                                           \
      BFL[n_] = *(const s16x8*)(lds + (SB1) * BSLOT + boff + n_ * 1024);     \
    kgA = (kgA + 1) & (NCH - 1);                                             \
    kgB = (kgB + 1) & (NCH - 1);                                             \
    __builtin_amdgcn_s_setprio(1);                                           \
    _Pragma("unroll")                                                        \
    for (int m_ = 0; m_ < 8; ++m_) {                                         \
      acc[m_][0] = MFMA(AFU[m_], BFU[0], acc[m_][0]);                        \
      acc[m_][1] = MFMA(AFU[m_], BFU[1], acc[m_][1]);                        \
      acc[m_][2] = MFMA(AFU[m_], BFU[2], acc[m_][2]);                        \
      acc[m_][3] = MFMA(AFU[m_], BFU[3], acc[m_][3]);                        \
    }                                                                        \
    __builtin_amdgcn_s_setprio(0);                                           \
    asm volatile("s_waitcnt vmcnt(10)" ::: "memory");                        \
    __builtin_amdgcn_s_barrier();                                            \
  }

__global__ __launch_bounds__(512, 2) void gemm256(
    const __hip_bfloat16* __restrict__ A,
    const __hip_bfloat16* __restrict__ B,
    const float* __restrict__ bias,
    float* __restrict__ C)
{
    __shared__ char lds[4 * BSLOT];   // 64 KiB, B ring only

    const int tid  = threadIdx.x;
    const int lane = tid & 63;
    const int wid  = tid >> 6;    // 0..7
    const int wm   = wid >> 2;    // 0..1  (M half)
    const int wn   = wid & 3;     // 0..3  (N quarter)

    // T1 (measured FETCH ~104 MB): XCD = bid%8 owns 8 row-panels x 8 cols
    // -> concurrent A working set = 4 MB = exactly L2; A lines fetched once.
    const int bid  = blockIdx.x;
    const int swz  = (bid & 7) * 64 + (bid >> 3);
    const int brow = (swz >> 3) * BM;
    const int bcol = (swz & 7) * BN;

    // ---- B staging: linear LDS dest, pre-swizzled global source (T2) ----
    // thread t writes 16B at slot-offset t*16 (row t>>2, phys k-slot t&3);
    // logical k-slot = (t&3) ^ ((t>>3)&3).  (measured: 0 bank conflicts)
    const int csw = (tid & 3) ^ ((tid >> 3) & 3);
    const __hip_bfloat16* Bs0 = B + (size_t)(bcol + (tid >> 2)) * KDIM + csw * 8;
    const __hip_bfloat16* Bs1 = Bs0 + (size_t)128 * KDIM;
    const int ldoff = tid * 16;

    // ---- fragment constants ----
    const int fr  = lane & 15;
    const int l16 = lane >> 4;
    // bf reads: swizzle inverse (lane-constant XOR)
    const int xr  = (l16 ^ ((fr >> 1) & 3)) * 16;
    const int boff = (wn * 64 + fr) * 64 + xr;
    // A direct: lane l reads A[row = brow + wm*128 + m*16 + fr]
    //                        [k = kgA*32 + l16*8 .. +8]  (== frag layout)
    const char* Abase = (const char*)(A
        + (size_t)(brow + wm * 128 + fr) * KDIM + l16 * 8);

    f32x4 acc[8][4];
    #pragma unroll
    for (int m = 0; m < 8; ++m)
        #pragma unroll
        for (int n = 0; n < 4; ++n)
            acc[m][n] = (f32x4){0.f, 0.f, 0.f, 0.f};

    s16x8 afA[8], afB[8], bfA[4], bfB[4];
    int kgA, kgB;

    // ---- prologue: A(0) -> regs; stage B(0..2); full drain; bf(0) ----
    #pragma unroll
    for (int m = 0; m < 8; ++m)
        afA[m] = *(const s16x8*)(Abase + (size_t)m * 65536);
    #pragma unroll
    for (int q = 0; q < 3; ++q) {
        gload_lds16(Bs0 + q * 32, lds + q * BSLOT + ldoff);
        gload_lds16(Bs1 + q * 32, lds + q * BSLOT + 8192 + ldoff);
    }
    kgA = 1; kgB = 3;
    asm volatile("s_waitcnt vmcnt(0)" ::: "memory");  // one-time full drain
    __builtin_amdgcn_s_barrier();
    #pragma unroll
    for (int n = 0; n < 4; ++n)
        bfA[n] = *(const s16x8*)(lds + boff + n * 1024);

    #pragma unroll 1
    for (int it = 0; it < NCH / 4; ++it) {
        CHUNK(afA, afB, bfA, bfB, 1, 3);   // chunk 4it
        CHUNK(afB, afA, bfB, bfA, 2, 0);   // chunk 4it+1
        CHUNK(afA, afB, bfA, bfB, 3, 1);   // chunk 4it+2
        CHUNK(afB, afA, bfB, bfA, 0, 2);   // chunk 4it+3
    }
    asm volatile("s_waitcnt vmcnt(0) lgkmcnt(0)" ::: "memory");

    // ---- epilogue: C/D layout col = lane&15, row = (lane>>4)*4 + j ----
    const int ccol0 = bcol + wn * 64 + fr;
    const int crow0 = brow + wm * 128 + l16 * 4;
    float bv[4];
    #pragma unroll
    for (int n = 0; n < 4; ++n) bv[n] = bias[ccol0 + n * 16];

    #pragma unroll
    for (int m = 0; m < 8; ++m) {
        #pragma unroll
        for (int j = 0; j < 4; ++j) {
            float* Crow = C + (size_t)(crow0 + m * 16 + j) * NDIM;
            #pragma unroll
            for (int n = 0; n < 4; ++n)
                Crow[ccol0 + n * 16] = acc[m][n][j] + bv[n];
        }
    }
}

// ---------------- launcher ----------------

extern "C" void kernel_launch(void* const* d_in, const int* in_sizes, int n_in,
                              void* d_out, int out_size, void* d_ws, size_t ws_size,
                              hipStream_t stream) {
    const float* x        = (const float*)d_in[0];  // [4,4096,2048]
    const float* weights  = (const float*)d_in[1];  // [16]
    const float* W        = (const float*)d_in[2];  // [2048,2048]
    const float* b        = (const float*)d_in[3];  // [2048]
    const float* a_scales = (const float*)d_in[4];  // [2]
    const float* w_scales = (const float*)d_in[5];  // [2]
    float* out = (float*)d_out;

    __hip_bfloat16* xq = (__hip_bfloat16*)d_ws;                            // 67108864 B
    __hip_bfloat16* wq = (__hip_bfloat16*)((char*)d_ws + 67108864);        //  8388608 B
    float*          bm = (float*)((char*)d_ws + 67108864 + 8388608);       //     8192 B

    prep_w<<<dim3((NDIM * KDIM) / (256 * 8)), dim3(256), 0, stream>>>(W, weights, w_scales, wq);
    prep_b<<<dim3(NDIM / 256), dim3(256), 0, stream>>>(b, weights, bm);
    prep_x<<<dim3(((size_t)MDIM * KDIM) / (256 * 8)), dim3(256), 0, stream>>>(x, weights, a_scales, xq);
    gemm256<<<dim3((MDIM / BM) * (NDIM / BN)), dim3(512), 0, stream>>>(xq, wq, bm, out);
}

// Round 10
// 174.325 us; speedup vs baseline: 1.9867x; 1.9867x over previous
//
#include <hip/hip_runtime.h>
#include <hip/hip_bf16.h>
#include <stdint.h>

#define MDIM 16384   // B*S = 4*4096
#define NDIM 2048    // MAX_OUT
#define KDIM 2048    // MAX_IN

typedef __attribute__((ext_vector_type(4))) float f32x4;
typedef __attribute__((ext_vector_type(8))) short s16x8;

__device__ __forceinline__ void gload_lds16(const __hip_bfloat16* g, void* l) {
    __builtin_amdgcn_global_load_lds(
        (const __attribute__((address_space(1))) void*)g,
        (__attribute__((address_space(3))) void*)l,
        16, 0, 0);
}

// ---------------- prep kernels (at HBM BW floor) ----------------

__global__ __launch_bounds__(256) void prep_x(
    const float* __restrict__ x, const float* __restrict__ weights,
    const float* __restrict__ a_scales, __hip_bfloat16* __restrict__ xq)
{
    float A0 = 0.f, A1 = 0.f;
    #pragma unroll
    for (int k = 0; k < 16; ++k) {
        float w = weights[k];
        if (((k >> 1) & 1) == 0) A0 += w; else A1 += w;
    }
    const float s0 = a_scales[0], s1 = a_scales[1];
    const float r0 = 1.f / s0, r1 = 1.f / s1;

    size_t idx = ((size_t)blockIdx.x * 256 + threadIdx.x) * 8;
    const f32x4* xv = (const f32x4*)(x + idx);
    f32x4 v0 = xv[0], v1 = xv[1];
    float vals[8] = {v0.x, v0.y, v0.z, v0.w, v1.x, v1.y, v1.z, v1.w};

    union { s16x8 v; __hip_bfloat16 h[8]; } u;
    #pragma unroll
    for (int j = 0; j < 8; ++j) {
        float q0 = rintf(fminf(fmaxf(vals[j] * r0, -8.f),   7.f)) * s0;
        float q1 = rintf(fminf(fmaxf(vals[j] * r1, -128.f), 127.f)) * s1;
        u.h[j] = __float2bfloat16(A0 * q0 + A1 * q1);
    }
    *(s16x8*)(xq + idx) = u.v;
}

__global__ __launch_bounds__(256) void prep_w(
    const float* __restrict__ W, const float* __restrict__ weights,
    const float* __restrict__ w_scales, __hip_bfloat16* __restrict__ wq)
{
    float c00 = weights[0] + weights[2]  + weights[4]  + weights[6];
    float c01 = weights[1] + weights[3]  + weights[5]  + weights[7];
    float c10 = weights[8] + weights[10] + weights[12] + weights[14];
    float c11 = weights[9] + weights[11] + weights[13] + weights[15];

    const float s0 = w_scales[0], s1 = w_scales[1];
    const float r0 = 1.f / s0, r1 = 1.f / s1;

    size_t idx = ((size_t)blockIdx.x * 256 + threadIdx.x) * 8;
    const int o = (int)(idx >> 11);
    const int c = (int)(idx & 2047);
    const bool inner = (o < 1024) && (c < 1024);
    const float k0 = inner ? (c00 + c10) : c10;
    const float k1 = inner ? (c01 + c11) : c11;

    const f32x4* wv = (const f32x4*)(W + idx);
    f32x4 v0 = wv[0], v1 = wv[1];
    float vals[8] = {v0.x, v0.y, v0.z, v0.w, v1.x, v1.y, v1.z, v1.w};

    union { s16x8 v; __hip_bfloat16 h[8]; } u;
    #pragma unroll
    for (int j = 0; j < 8; ++j) {
        float q0 = rintf(fminf(fmaxf(vals[j] * r0, -8.f),   7.f)) * s0;
        float q1 = rintf(fminf(fmaxf(vals[j] * r1, -128.f), 127.f)) * s1;
        u.h[j] = __float2bfloat16(k0 * q0 + k1 * q1);
    }
    *(s16x8*)(wq + idx) = u.v;
}

__global__ __launch_bounds__(256) void prep_b(
    const float* __restrict__ b, const float* __restrict__ weights,
    float* __restrict__ bm)
{
    int o = blockIdx.x * 256 + threadIdx.x;
    if (o >= NDIM) return;
    float S1 = 0.f, S0 = 0.f;
    #pragma unroll
    for (int k = 0; k < 8; ++k)  S0 += weights[k];
    #pragma unroll
    for (int k = 8; k < 16; ++k) S1 += weights[k];
    bm[o] = b[o] * ((o < 1024) ? (S0 + S1) : S1);
}

// ---------------- GEMM: 128x256 tile, 4 waves (wave tile 128x64),
// ring-3 LDS (72 KB) -> 2 independent blocks/CU: inter-block TLP overlaps
// one block's LDS/barrier phase with the other's MFMA phase (m114).
// Chunk body = R7 structure: frag reads + stage(c+2) + 32 MFMA + vmcnt(6)
// + barrier; compiler schedules reads/MFMA interleave from dataflow. ----

#define NCH 64           // K chunks of 32
#define ASLOT 8192       // A slot: 128 rows x 64 B
#define BSLOT 16384      // B slot: 256 rows x 64 B
#define BREG  24576      // B region base (3 A slots first); total 73728 B

#define MFMA(a, b, c) __builtin_amdgcn_mfma_f32_16x16x32_bf16((a), (b), (c), 0, 0, 0)

// S = c%3 (compute slot), T = (c+2)%3 (stage slot).
#define CHUNK(S, T)                                                          \
  {                                                                          \
    asm volatile("" ::: "memory");  /* no hoist of reads above barrier */    \
    s16x8 af[8], bf[4];                                                      \
    _Pragma("unroll")                                                        \
    for (int m_ = 0; m_ < 8; ++m_)                                           \
      af[m_] = *(const s16x8*)(lds + (S) * ASLOT + aoff + m_ * 1024);        \
    _Pragma("unroll")                                                        \
    for (int n_ = 0; n_ < 4; ++n_)                                           \
      bf[n_] = *(const s16x8*)(lds + BREG + (S) * BSLOT + boff + n_ * 1024); \
    gload_lds16(As + kg * 32,                lds + (T) * ASLOT + ldoff);     \
    gload_lds16(As + 64 * KDIM + kg * 32,    lds + (T) * ASLOT + 4096 + ldoff); \
    _Pragma("unroll")                                                        \
    for (int q_ = 0; q_ < 4; ++q_)                                           \
      gload_lds16(Bs + q_ * 64 * KDIM + kg * 32,                             \
                  lds + BREG + (T) * BSLOT + q_ * 4096 + ldoff);             \
    kg = (kg + 1) & (NCH - 1);                                               \
    __builtin_amdgcn_s_setprio(1);                                           \
    _Pragma("unroll")                                                        \
    for (int m_ = 0; m_ < 8; ++m_) {                                         \
      acc[m_][0] = MFMA(af[m_], bf[0], acc[m_][0]);                          \
      acc[m_][1] = MFMA(af[m_], bf[1], acc[m_][1]);                          \
      acc[m_][2] = MFMA(af[m_], bf[2], acc[m_][2]);                          \
      acc[m_][3] = MFMA(af[m_], bf[3], acc[m_][3]);                          \
    }                                                                        \
    __builtin_amdgcn_s_setprio(0);                                           \
    asm volatile("s_waitcnt vmcnt(6)" ::: "memory");  /* c+1 landed */       \
    __builtin_amdgcn_s_barrier();                                            \
  }

__global__ __launch_bounds__(256, 2) void gemm128x256(
    const __hip_bfloat16* __restrict__ A,
    const __hip_bfloat16* __restrict__ B,
    const float* __restrict__ bias,
    float* __restrict__ C)
{
    __shared__ char lds[3 * ASLOT + 3 * BSLOT];   // 73728 B

    const int tid  = threadIdx.x;
    const int lane = tid & 63;
    const int wn   = tid >> 6;    // 0..3  (N quarter); all waves share A rows

    // T1: 1024 blocks, 128/XCD = 16 row-panels x 8 cols -> resident A/XCD
    // = 4 MB = L2; B (8 MB) L3-hot.
    const int bid  = blockIdx.x;
    const int swz  = (bid & 7) * 128 + (bid >> 3);
    const int brow = (swz >> 3) * 128;
    const int bcol = (swz & 7) * 256;

    // ---- staging: linear LDS dest, pre-swizzled global source (T2) ----
    // 16B unit: row r = t>>2 (+64q), phys k-slot t&3; logical = (t&3)^((r>>1)&3).
    const int csw = (tid & 3) ^ ((tid >> 3) & 3);
    const __hip_bfloat16* As = A + (size_t)(brow + (tid >> 2)) * KDIM + csw * 8;
    const __hip_bfloat16* Bs = B + (size_t)(bcol + (tid >> 2)) * KDIM + csw * 8;
    const int ldoff = tid * 16;

    // ---- fragment-read constants (swizzle inverse; lane-constant XOR) ----
    const int fr  = lane & 15;
    const int l16 = lane >> 4;
    const int xr  = (l16 ^ ((fr >> 1) & 3)) * 16;
    const int aoff = fr * 64 + xr;                 // + m*1024 (rows m*16+fr)
    const int boff = (wn * 64 + fr) * 64 + xr;     // + n*1024

    f32x4 acc[8][4];
    #pragma unroll
    for (int m = 0; m < 8; ++m)
        #pragma unroll
        for (int n = 0; n < 4; ++n)
            acc[m][n] = (f32x4){0.f, 0.f, 0.f, 0.f};

    int kg;

    // ---- prologue: stage chunks 0,1 into slots 0,1; gate chunk 0 ----
    #pragma unroll
    for (int q = 0; q < 2; ++q) {
        gload_lds16(As + q * 32,             lds + q * ASLOT + ldoff);
        gload_lds16(As + 64 * KDIM + q * 32, lds + q * ASLOT + 4096 + ldoff);
        #pragma unroll
        for (int p = 0; p < 4; ++p)
            gload_lds16(Bs + p * 64 * KDIM + q * 32,
                        lds + BREG + q * BSLOT + p * 4096 + ldoff);
    }
    kg = 2;
    asm volatile("s_waitcnt vmcnt(6)" ::: "memory");  // chunk 0 landed
    __builtin_amdgcn_s_barrier();

    // chunks 0..62 in 21 slot-triples, then chunk 63 (slot 0; wrap stage dead)
    #pragma unroll 1
    for (int it = 0; it < 21; ++it) {
        CHUNK(0, 2);
        CHUNK(1, 0);
        CHUNK(2, 1);
    }
    CHUNK(0, 2);   // chunk 63
    asm volatile("s_waitcnt vmcnt(0) lgkmcnt(0)" ::: "memory");

    // ---- epilogue: C/D layout col = lane&15, row = (lane>>4)*4 + j ----
    const int ccol0 = bcol + wn * 64 + fr;
    const int crow0 = brow + l16 * 4;
    float bv[4];
    #pragma unroll
    for (int n = 0; n < 4; ++n) bv[n] = bias[ccol0 + n * 16];

    #pragma unroll
    for (int m = 0; m < 8; ++m) {
        #pragma unroll
        for (int j = 0; j < 4; ++j) {
            float* Crow = C + (size_t)(crow0 + m * 16 + j) * NDIM;
            #pragma unroll
            for (int n = 0; n < 4; ++n)
                Crow[ccol0 + n * 16] = acc[m][n][j] + bv[n];
        }
    }
}

// ---------------- launcher ----------------

extern "C" void kernel_launch(void* const* d_in, const int* in_sizes, int n_in,
                              void* d_out, int out_size, void* d_ws, size_t ws_size,
                              hipStream_t stream) {
    const float* x        = (const float*)d_in[0];  // [4,4096,2048]
    const float* weights  = (const float*)d_in[1];  // [16]
    const float* W        = (const float*)d_in[2];  // [2048,2048]
    const float* b        = (const float*)d_in[3];  // [2048]
    const float* a_scales = (const float*)d_in[4];  // [2]
    const float* w_scales = (const float*)d_in[5];  // [2]
    float* out = (float*)d_out;

    __hip_bfloat16* xq = (__hip_bfloat16*)d_ws;                            // 67108864 B
    __hip_bfloat16* wq = (__hip_bfloat16*)((char*)d_ws + 67108864);        //  8388608 B
    float*          bm = (float*)((char*)d_ws + 67108864 + 8388608);       //     8192 B

    prep_w<<<dim3((NDIM * KDIM) / (256 * 8)), dim3(256), 0, stream>>>(W, weights, w_scales, wq);
    prep_b<<<dim3(NDIM / 256), dim3(256), 0, stream>>>(b, weights, bm);
    prep_x<<<dim3(((size_t)MDIM * KDIM) / (256 * 8)), dim3(256), 0, stream>>>(x, weights, a_scales, xq);
    gemm128x256<<<dim3((MDIM / 128) * (NDIM / 256)), dim3(256), 0, stream>>>(xq, wq, bm, out);
}

// Round 11
// 163.759 us; speedup vs baseline: 2.1149x; 1.0645x over previous
//
#include <hip/hip_runtime.h>
#include <hip/hip_bf16.h>
#include <stdint.h>

#define MDIM 16384   // B*S = 4*4096
#define NDIM 2048    // MAX_OUT
#define KDIM 2048    // MAX_IN

typedef __attribute__((ext_vector_type(4))) float f32x4;
typedef __attribute__((ext_vector_type(8))) short s16x8;

__device__ __forceinline__ void gload_lds16(const __hip_bfloat16* g, void* l) {
    __builtin_amdgcn_global_load_lds(
        (const __attribute__((address_space(1))) void*)g,
        (__attribute__((address_space(3))) void*)l,
        16, 0, 0);
}

// ---------------- prep kernels (at HBM BW floor) ----------------

__global__ __launch_bounds__(256) void prep_x(
    const float* __restrict__ x, const float* __restrict__ weights,
    const float* __restrict__ a_scales, __hip_bfloat16* __restrict__ xq)
{
    float A0 = 0.f, A1 = 0.f;
    #pragma unroll
    for (int k = 0; k < 16; ++k) {
        float w = weights[k];
        if (((k >> 1) & 1) == 0) A0 += w; else A1 += w;
    }
    const float s0 = a_scales[0], s1 = a_scales[1];
    const float r0 = 1.f / s0, r1 = 1.f / s1;

    size_t idx = ((size_t)blockIdx.x * 256 + threadIdx.x) * 8;
    const f32x4* xv = (const f32x4*)(x + idx);
    f32x4 v0 = xv[0], v1 = xv[1];
    float vals[8] = {v0.x, v0.y, v0.z, v0.w, v1.x, v1.y, v1.z, v1.w};

    union { s16x8 v; __hip_bfloat16 h[8]; } u;
    #pragma unroll
    for (int j = 0; j < 8; ++j) {
        float q0 = rintf(fminf(fmaxf(vals[j] * r0, -8.f),   7.f)) * s0;
        float q1 = rintf(fminf(fmaxf(vals[j] * r1, -128.f), 127.f)) * s1;
        u.h[j] = __float2bfloat16(A0 * q0 + A1 * q1);
    }
    *(s16x8*)(xq + idx) = u.v;
}

__global__ __launch_bounds__(256) void prep_w(
    const float* __restrict__ W, const float* __restrict__ weights,
    const float* __restrict__ w_scales, __hip_bfloat16* __restrict__ wq)
{
    float c00 = weights[0] + weights[2]  + weights[4]  + weights[6];
    float c01 = weights[1] + weights[3]  + weights[5]  + weights[7];
    float c10 = weights[8] + weights[10] + weights[12] + weights[14];
    float c11 = weights[9] + weights[11] + weights[13] + weights[15];

    const float s0 = w_scales[0], s1 = w_scales[1];
    const float r0 = 1.f / s0, r1 = 1.f / s1;

    size_t idx = ((size_t)blockIdx.x * 256 + threadIdx.x) * 8;
    const int o = (int)(idx >> 11);
    const int c = (int)(idx & 2047);
    const bool inner = (o < 1024) && (c < 1024);
    const float k0 = inner ? (c00 + c10) : c10;
    const float k1 = inner ? (c01 + c11) : c11;

    const f32x4* wv = (const f32x4*)(W + idx);
    f32x4 v0 = wv[0], v1 = wv[1];
    float vals[8] = {v0.x, v0.y, v0.z, v0.w, v1.x, v1.y, v1.z, v1.w};

    union { s16x8 v; __hip_bfloat16 h[8]; } u;
    #pragma unroll
    for (int j = 0; j < 8; ++j) {
        float q0 = rintf(fminf(fmaxf(vals[j] * r0, -8.f),   7.f)) * s0;
        float q1 = rintf(fminf(fmaxf(vals[j] * r1, -128.f), 127.f)) * s1;
        u.h[j] = __float2bfloat16(k0 * q0 + k1 * q1);
    }
    *(s16x8*)(wq + idx) = u.v;
}

__global__ __launch_bounds__(256) void prep_b(
    const float* __restrict__ b, const float* __restrict__ weights,
    float* __restrict__ bm)
{
    int o = blockIdx.x * 256 + threadIdx.x;
    if (o >= NDIM) return;
    float S1 = 0.f, S0 = 0.f;
    #pragma unroll
    for (int k = 0; k < 8; ++k)  S0 += weights[k];
    #pragma unroll
    for (int k = 8; k < 16; ++k) S1 += weights[k];
    bm[o] = b[o] * ((o < 1024) ? (S0 + S1) : S1);
}

// ---------------- GEMM: 256x256 tile, BK=64, dbuf-2 (128 KB), 8 waves,
// faithful m201 8-phase schedule:
//  per tile t (slot SL), quadrants (mh,kh) in order (0,0)(1,0)(0,1)(1,1):
//  phase = { ds_read af[4] (+bf[4] on kh-entry) | stage 1 half-tile of t+1
//            (2 gloads, order A0,B0,A1,B1 across P1..P4) | vmcnt(4) at P2,P4
//            | barrier | lgkmcnt(0) | setprio(1) 16 MFMA setprio(0) | barrier }
//  vmcnt(4) at P2 drains {A1,B1}(t) for P3; at P4 drains {A0,B0}(t+1) for
//  P1(t+1); halves stay 3-4 phases in flight, never drained to 0 (T4).
//  kh-region death mid-tile makes the continuous staging WAR-safe. ----

#define NT 32            // K-tiles of 64
#define REGION 16384     // bytes per kh-region (256 r x 32 k x 2B)
#define SLOTB  65536     // bytes per tile slot (4 regions)

#define MFMA(a, b, c) __builtin_amdgcn_mfma_f32_16x16x32_bf16((a), (b), (c), 0, 0, 0)

// SL: tile slot. MH,KH: quadrant. RD_BF: load bf (kh-entry phases).
// STG_B: stage B-half (else A). STG_KH: kh of the staged half. DO_VM: vmcnt.
#define PHASE(SL, MH, KH, RD_BF, STG_B, STG_KH, DO_VM)                       \
  {                                                                          \
    const char* pa_ = lds + (SL) * SLOTB + (KH) * REGION;                    \
    _Pragma("unroll")                                                        \
    for (int i_ = 0; i_ < 4; ++i_)                                           \
      af[i_] = *(const s16x8*)(pa_ + (MH) * 4096 + i_ * 1024 + aoff);        \
    if (RD_BF) {                                                             \
      const char* pb_ = lds + (SL) * SLOTB + (2 + (KH)) * REGION;            \
      _Pragma("unroll")                                                      \
      for (int n_ = 0; n_ < 4; ++n_)                                         \
        bf[n_] = *(const s16x8*)(pb_ + n_ * 1024 + boff);                    \
    }                                                                        \
    {                                                                        \
      char* d_ = lds + ((SL) ^ 1) * SLOTB                                    \
               + ((STG_B) ? (2 + (STG_KH)) : (STG_KH)) * REGION + ldoff;     \
      const __hip_bfloat16* s_ = ((STG_B) ? Bs : As) + kg * 64 + (STG_KH) * 32; \
      gload_lds16(s_, d_);                                                   \
      gload_lds16(s_ + (size_t)128 * KDIM, d_ + 8192);                       \
    }                                                                        \
    if (DO_VM) asm volatile("s_waitcnt vmcnt(4)" ::: "memory");              \
    __builtin_amdgcn_s_barrier();                                            \
    asm volatile("s_waitcnt lgkmcnt(0)" ::: "memory");                       \
    __builtin_amdgcn_s_setprio(1);                                           \
    _Pragma("unroll")                                                        \
    for (int i_ = 0; i_ < 4; ++i_) {                                         \
      acc[(MH)*4+i_][0] = MFMA(af[i_], bf[0], acc[(MH)*4+i_][0]);            \
      acc[(MH)*4+i_][1] = MFMA(af[i_], bf[1], acc[(MH)*4+i_][1]);            \
      acc[(MH)*4+i_][2] = MFMA(af[i_], bf[2], acc[(MH)*4+i_][2]);            \
      acc[(MH)*4+i_][3] = MFMA(af[i_], bf[3], acc[(MH)*4+i_][3]);            \
    }                                                                        \
    __builtin_amdgcn_s_setprio(0);                                           \
    __builtin_amdgcn_s_barrier();                                            \
  }

#define KTILE(SL)                                                            \
    PHASE(SL, 0, 0, 1, 0, 0, 0);  /* P1: read A0,B0(t); stage A-kh0(t+1) */  \
    PHASE(SL, 1, 0, 0, 1, 0, 1);  /* P2: stage B-kh0(t+1); vmcnt(4) */       \
    PHASE(SL, 0, 1, 1, 0, 1, 0);  /* P3: read A1,B1(t); stage A-kh1(t+1) */  \
    PHASE(SL, 1, 1, 0, 1, 1, 1);  /* P4: stage B-kh1(t+1); vmcnt(4) */       \
    kg = (kg + 1) & (NT - 1);

__global__ __launch_bounds__(512, 2) void gemm256(
    const __hip_bfloat16* __restrict__ A,
    const __hip_bfloat16* __restrict__ B,
    const float* __restrict__ bias,
    float* __restrict__ C)
{
    __shared__ char lds[2 * SLOTB];   // 128 KiB

    const int tid  = threadIdx.x;
    const int lane = tid & 63;
    const int wid  = tid >> 6;    // 0..7
    const int wm   = wid >> 2;    // 0..1  (M half)
    const int wn   = wid & 3;     // 0..3  (N quarter)

    // T1 (measured FETCH ~104 MB): XCD = bid%8 owns 8 row-panels x 8 cols.
    const int bid  = blockIdx.x;
    const int swz  = (bid & 7) * 64 + (bid >> 3);
    const int brow = (swz >> 3) * 256;
    const int bcol = (swz & 7) * 256;

    // ---- staging: linear LDS dest, pre-swizzled global source (T2) ----
    // region unit u = tid + 512g: row = u>>2 (256), phys slot = u&3;
    // logical k-slot = (u&3) ^ ((row>>1)&3).  (measured: 0 bank conflicts)
    const int csw = (tid & 3) ^ ((tid >> 3) & 3);
    const __hip_bfloat16* As = A + (size_t)(brow + (tid >> 2)) * KDIM + csw * 8;
    const __hip_bfloat16* Bs = B + (size_t)(bcol + (tid >> 2)) * KDIM + csw * 8;
    const int ldoff = tid * 16;

    // ---- fragment-read constants (swizzle inverse; lane-constant XOR) ----
    const int fr  = lane & 15;
    const int l16 = lane >> 4;
    const int xr  = (l16 ^ ((fr >> 1) & 3)) * 16;
    const int aoff = wm * 8192 + fr * 64 + xr;   // + MH*4096 + i*1024
    const int boff = wn * 4096 + fr * 64 + xr;   // + n*1024

    f32x4 acc[8][4];
    #pragma unroll
    for (int m = 0; m < 8; ++m)
        #pragma unroll
        for (int n = 0; n < 4; ++n)
            acc[m][n] = (f32x4){0.f, 0.f, 0.f, 0.f};

    s16x8 af[4], bf[4];
    int kg = 1;   // tile to stage during the current tile

    // ---- prologue: stage tile 0's halves in FIFO order A0,B0,A1,B1 ----
    {
        #pragma unroll
        for (int h = 0; h < 4; ++h) {           // h: 0=A0 1=B0 2=A1 3=B1
            const int  kh = h >> 1;             // order A0,B0,A1,B1
            const int  isB = h & 1;
            char* d = lds + (isB ? (2 + kh) : kh) * REGION + ldoff;
            const __hip_bfloat16* s = (isB ? Bs : As) + kh * 32;
            gload_lds16(s, d);
            gload_lds16(s + (size_t)128 * KDIM, d + 8192);
        }
    }
    asm volatile("s_waitcnt vmcnt(4)" ::: "memory");  // A0,B0(t0) landed
    __builtin_amdgcn_s_barrier();

    #pragma unroll 1
    for (int it = 0; it < NT / 2; ++it) {
        KTILE(0);   // tile 2it   (slot 0)
        KTILE(1);   // tile 2it+1 (slot 1)
    }
    asm volatile("s_waitcnt vmcnt(0) lgkmcnt(0)" ::: "memory");

    // ---- epilogue: C/D layout col = lane&15, row = (lane>>4)*4 + j ----
    const int ccol0 = bcol + wn * 64 + fr;
    const int crow0 = brow + wm * 128 + l16 * 4;
    float bv[4];
    #pragma unroll
    for (int n = 0; n < 4; ++n) bv[n] = bias[ccol0 + n * 16];

    #pragma unroll
    for (int m = 0; m < 8; ++m) {
        #pragma unroll
        for (int j = 0; j < 4; ++j) {
            float* Crow = C + (size_t)(crow0 + m * 16 + j) * NDIM;
            #pragma unroll
            for (int n = 0; n < 4; ++n)
                Crow[ccol0 + n * 16] = acc[m][n][j] + bv[n];
        }
    }
}

// ---------------- launcher ----------------

extern "C" void kernel_launch(void* const* d_in, const int* in_sizes, int n_in,
                              void* d_out, int out_size, void* d_ws, size_t ws_size,
                              hipStream_t stream) {
    const float* x        = (const float*)d_in[0];  // [4,4096,2048]
    const float* weights  = (const float*)d_in[1];  // [16]
    const float* W        = (const float*)d_in[2];  // [2048,2048]
    const float* b        = (const float*)d_in[3];  // [2048]
    const float* a_scales = (const float*)d_in[4];  // [2]
    const float* w_scales = (const float*)d_in[5];  // [2]
    float* out = (float*)d_out;

    __hip_bfloat16* xq = (__hip_bfloat16*)d_ws;                            // 67108864 B
    __hip_bfloat16* wq = (__hip_bfloat16*)((char*)d_ws + 67108864);        //  8388608 B
    float*          bm = (float*)((char*)d_ws + 67108864 + 8388608);       //     8192 B

    prep_w<<<dim3((NDIM * KDIM) / (256 * 8)), dim3(256), 0, stream>>>(W, weights, w_scales, wq);
    prep_b<<<dim3(NDIM / 256), dim3(256), 0, stream>>>(b, weights, bm);
    prep_x<<<dim3(((size_t)MDIM * KDIM) / (256 * 8)), dim3(256), 0, stream>>>(x, weights, a_scales, xq);
    gemm256<<<dim3((MDIM / 256) * (NDIM / 256)), dim3(512), 0, stream>>>(xq, wq, bm, out);
}